// Round 3
// baseline (813.380 us; speedup 1.0000x reference)
//
#include <hip/hip_runtime.h>
#include <cstdint>
#include <cstddef>

typedef _Float16 f16;
typedef _Float16 f16x8 __attribute__((ext_vector_type(8)));
typedef float f32x4 __attribute__((ext_vector_type(4)));

// ---------------------------------------------------------------------------
// async global->LDS, 16B per lane. LDS dest is wave-uniform base + lane*16.
// ---------------------------------------------------------------------------
__device__ __forceinline__ void async16(const void* g, void* l) {
  __builtin_amdgcn_global_load_lds(
      (const __attribute__((address_space(1))) unsigned int*)g,
      (__attribute__((address_space(3))) unsigned int*)l,
      16, 0, 0);
}

// ---------------------------------------------------------------------------
// Weight prep: Wt[o][i*8+g] = coef[i][o][g] * ssp[i][o]   (Wt is [O][K], K=I*9)
// ---------------------------------------------------------------------------
template <int I, int O>
__global__ void prep_coef(const float* __restrict__ coef,
                          const float* __restrict__ ssp,
                          f16* __restrict__ Wt) {
  int tid = blockIdx.x * 256 + threadIdx.x;
  if (tid >= I * O) return;
  int i = tid / O, o = tid % O;             // o fastest -> coalesced coef reads
  float s = ssp[tid];
  const float* c = coef + (size_t)tid * 8;
  f16x8 out;
#pragma unroll
  for (int g = 0; g < 8; ++g) out[g] = (f16)(c[g] * s);
  *(f16x8*)(Wt + (size_t)o * (I * 9) + (size_t)i * 8) = out;
}

// Wt[o][I*8+i] = sb[i][o]
template <int I, int O>
__global__ void prep_base(const float* __restrict__ sb, f16* __restrict__ Wt) {
  int tid = blockIdx.x * 256 + threadIdx.x;
  if (tid >= I * O) return;
  int o = tid / I, i = tid % I;             // i fastest -> coalesced Wt writes
  Wt[(size_t)o * (I * 9) + (size_t)I * 8 + i] = (f16)sb[(size_t)i * O + o];
}

// ---------------------------------------------------------------------------
// 8-slot cubic B-spline basis of one scalar, partition-of-unity form.
// slot g = M(2.5h+5.5-g), M = uniform cubic on (0,4). With c=floor(v), f=v-c:
// nonzero slots are g=c-3..c with values b0=(1-f)^3/6, b1=2/3-f^2+f^3/2,
// b2=1-b0-b1-b3 (partition of unity), b3=f^3/6.  Verified vs Horner form
// (R1/R2 passed absmax 0.0625): M(2)=2/3, M(2.5)=0.479, M(3)=1/6 all match.
// ---------------------------------------------------------------------------
__device__ __forceinline__ f16x8 spline8(float h) {
  float v = __builtin_fmaf(2.5f, h, 5.5f);
  float c = floorf(v);
  float f = v - c;
  float f2 = f * f, f3 = f2 * f;
  float b3 = f3 * (1.f / 6.f);
  float t = 1.f - f;
  float b0 = t * t * t * (1.f / 6.f);
  float b1 = (2.f / 3.f) - f2 + 0.5f * f3;
  float b2 = 1.f - b0 - b1 - b3;
  int base = 3 - (int)c;
  f16x8 o;
#pragma unroll
  for (int g = 0; g < 8; ++g) {
    int d = base + g;                         // 0..3 -> b_d else 0
    float lo = (d & 2) ? b2 : b0;
    float hi = (d & 2) ? b3 : b1;
    float val = (d & 1) ? hi : lo;
    o[g] = (f16)(((unsigned)d <= 3u) ? val : 0.f);
  }
  return o;
}

// ---------------------------------------------------------------------------
// Fused KAN GEMM: C[M,N](f32) = KanAct(H)[M,9I] @ W[N,9I]^T, where
// KanAct(H)[m, i*8+g] = basis_g(H[m,i]) and KanAct(H)[m, 8I+i] = silu(H[m,i]).
// A-tiles are computed on the fly from H (fp32) into swizzled LDS — no
// materialized activation matrix. B staged via global_load_lds width-16.
// 128x128 tile, BK=64, mfma_f32_16x16x32_f16, 4 waves * 4x4 accs.
// LDS XOR swizzle on 16B chunks: LDS[r][c] = logical chunk c ^ (r&7).
// ATOMIC=1: atomicAdd epilogue for split-K (blockIdx.z * kChunk).
// ---------------------------------------------------------------------------
template <int I, int ATOMIC>
__global__ __launch_bounds__(256) void gemm_kan(const float* __restrict__ H,
                                                const f16* __restrict__ W,
                                                float* __restrict__ C,
                                                int N, int kChunk) {
  constexpr int K = 9 * I;
  constexpr int KB = 8 * I;                   // spline/base boundary (mult 64)
  __shared__ __align__(16) f16 sA[128 * 64];
  __shared__ __align__(16) f16 sB[128 * 64];
  const int t = threadIdx.x;
  const int n0 = blockIdx.x * 128;
  const int m0 = blockIdx.y * 128;
  const int kBeg = blockIdx.z * kChunk;
  const int kEnd = kBeg + kChunk;
  const int w = t >> 6, lane = t & 63;
  const int wm = (w >> 1) * 64, wn = (w & 1) * 64;
  const int lr = lane & 15, lq = lane >> 4;
  const int wbase = t & 192;                  // w*64, wave-uniform
  const int srow = t >> 3;                    // staging row 0..31 (q adds 32)
  const int j_ = t & 7;                       // chunk col 0..7
  const int js = j_ ^ (srow & 7);             // swizzled chunk col (inv. to +32)

  f32x4 acc[4][4] = {};
  const f16* Wrow = W + (size_t)(n0 + srow) * K + js * 8;
  const float* Hrow = H + (size_t)(m0 + srow) * I;

  for (int k0 = kBeg; k0 < kEnd; k0 += 64) {
    // B tile: async global->LDS (swizzled source column per lane)
#pragma unroll
    for (int q = 0; q < 4; ++q)
      async16(Wrow + (size_t)(q * 32) * K + k0, &sB[(q * 256 + wbase) * 8]);

    // A tile: compute from H. Whole block takes same branch (k0-uniform).
    if (k0 < KB) {
      const int i0 = k0 >> 3;                 // tile covers inputs i0..i0+7
      float hq[4];
#pragma unroll
      for (int q = 0; q < 4; ++q)
        hq[q] = Hrow[(size_t)(q * 32) * I + i0 + j_];
#pragma unroll
      for (int q = 0; q < 4; ++q)
        *(f16x8*)&sA[((q * 32 + srow) * 8 + js) * 8] = spline8(hq[q]);
    } else {
      const int c0 = (k0 - KB) + j_ * 8;      // 8 consecutive silu inputs
      f32x4 ha[4][2];
#pragma unroll
      for (int q = 0; q < 4; ++q) {
        const f32x4* p = (const f32x4*)(Hrow + (size_t)(q * 32) * I + c0);
        ha[q][0] = p[0];
        ha[q][1] = p[1];
      }
#pragma unroll
      for (int q = 0; q < 4; ++q) {
        f16x8 o;
#pragma unroll
        for (int s = 0; s < 8; ++s) {
          float h = ha[q][s >> 2][s & 3];
          o[s] = (f16)(h / (1.f + __expf(-h)));
        }
        *(f16x8*)&sA[((q * 32 + srow) * 8 + js) * 8] = o;
      }
    }
    __syncthreads();
#pragma unroll
    for (int kk = 0; kk < 64; kk += 32) {
      f16x8 av[4], bv[4];
#pragma unroll
      for (int i = 0; i < 4; ++i) {
        const int ra = wm + i * 16 + lr;
        const int ca = ((kk >> 3) + lq) ^ (ra & 7);
        av[i] = *(const f16x8*)&sA[ra * 64 + ca * 8];
      }
#pragma unroll
      for (int j = 0; j < 4; ++j) {
        const int rb = wn + j * 16 + lr;
        const int cb = ((kk >> 3) + lq) ^ (rb & 7);
        bv[j] = *(const f16x8*)&sB[rb * 64 + cb * 8];
      }
#pragma unroll
      for (int i = 0; i < 4; ++i)
#pragma unroll
        for (int j = 0; j < 4; ++j)
          acc[i][j] = __builtin_amdgcn_mfma_f32_16x16x32_f16(av[i], bv[j],
                                                             acc[i][j], 0, 0, 0);
    }
    __syncthreads();
  }

#pragma unroll
  for (int i = 0; i < 4; ++i) {
#pragma unroll
    for (int j = 0; j < 4; ++j) {
      const int col = n0 + wn + j * 16 + lr;
#pragma unroll
      for (int r = 0; r < 4; ++r) {
        const int row = m0 + wm + i * 16 + lq * 4 + r;
        if (ATOMIC)
          atomicAdd(&C[(size_t)row * N + col], acc[i][j][r]);
        else
          C[(size_t)row * N + col] = acc[i][j][r];
      }
    }
  }
}

// ---------------------------------------------------------------------------
extern "C" void kernel_launch(void* const* d_in, const int* in_sizes, int n_in,
                              void* d_out, int out_size, void* d_ws,
                              size_t ws_size, hipStream_t stream) {
  const float* x     = (const float*)d_in[0];
  const float* coef1 = (const float*)d_in[1];
  const float* sb1   = (const float*)d_in[2];
  const float* ssp1  = (const float*)d_in[3];
  const float* coef2 = (const float*)d_in[4];
  const float* sb2   = (const float*)d_in[5];
  const float* ssp2  = (const float*)d_in[6];

  const int Mtot = 8192;
  const int I1 = 512, O1 = 2048, K1 = I1 * 9;   // 4608
  const int I2 = 2048, O2 = 512, K2 = I2 * 9;   // 18432

  char* ws = (char*)d_ws;
  const size_t szW1 = (size_t)O1 * K1 * sizeof(f16);     // 18.9 MB
  const size_t szW2 = (size_t)O2 * K2 * sizeof(f16);     // 18.9 MB
  const size_t szH  = (size_t)Mtot * O1 * sizeof(float); // 67.1 MB
  if (ws_size < szW1 + szW2 + szH) return;  // cannot run; fail visibly
  f16*   W1 = (f16*)ws;
  f16*   W2 = (f16*)(ws + szW1);
  float* h1 = (float*)(ws + szW1 + szW2);

  // weight prep
  {
    int n1 = I1 * O1;
    prep_coef<512, 2048><<<(n1 + 255) / 256, 256, 0, stream>>>(coef1, ssp1, W1);
    prep_base<512, 2048><<<(n1 + 255) / 256, 256, 0, stream>>>(sb1, W1);
    int n2 = I2 * O2;
    prep_coef<2048, 512><<<(n2 + 255) / 256, 256, 0, stream>>>(coef2, ssp2, W2);
    prep_base<2048, 512><<<(n2 + 255) / 256, 256, 0, stream>>>(sb2, W2);
  }

  // layer 1: h1 = KanAct(x) @ W1^T   — grid 16x64 = 1024 blocks
  gemm_kan<512, 0><<<dim3(O1 / 128, Mtot / 128, 1), 256, 0, stream>>>(
      x, W1, h1, O1, K1);

  // layer 2: out = KanAct(h1) @ W2^T — split-K=4, grid 4x64x4 = 1024 blocks
  hipMemsetAsync(d_out, 0, (size_t)Mtot * O2 * sizeof(float), stream);
  const int SK = 4;
  gemm_kan<2048, 1><<<dim3(O2 / 128, Mtot / 128, SK), 256, 0, stream>>>(
      h1, W2, (float*)d_out, O2, K2 / SK);
}

// Round 4
// 600.641 us; speedup vs baseline: 1.3542x; 1.3542x over previous
//
#include <hip/hip_runtime.h>
#include <cstdint>
#include <cstddef>

typedef _Float16 f16;
typedef _Float16 f16x8 __attribute__((ext_vector_type(8)));
typedef float f32x4 __attribute__((ext_vector_type(4)));

// ---------------------------------------------------------------------------
// async global->LDS, 16B per lane. LDS dest is wave-uniform base + lane*16.
// ---------------------------------------------------------------------------
__device__ __forceinline__ void async16(const void* g, void* l) {
  __builtin_amdgcn_global_load_lds(
      (const __attribute__((address_space(1))) unsigned int*)g,
      (__attribute__((address_space(3))) unsigned int*)l,
      16, 0, 0);
}

// ---------------------------------------------------------------------------
// Weight prep: Wt[o][i*8+g] = coef[i][o][g] * ssp[i][o]   (Wt is [O][K], K=I*9)
// ---------------------------------------------------------------------------
template <int I, int O>
__global__ void prep_coef(const float* __restrict__ coef,
                          const float* __restrict__ ssp,
                          f16* __restrict__ Wt) {
  int tid = blockIdx.x * 256 + threadIdx.x;
  if (tid >= I * O) return;
  int i = tid / O, o = tid % O;             // o fastest -> coalesced coef reads
  float s = ssp[tid];
  const float* c = coef + (size_t)tid * 8;
  f16x8 out;
#pragma unroll
  for (int g = 0; g < 8; ++g) out[g] = (f16)(c[g] * s);
  *(f16x8*)(Wt + (size_t)o * (I * 9) + (size_t)i * 8) = out;
}

// Wt[o][I*8+i] = sb[i][o]
template <int I, int O>
__global__ void prep_base(const float* __restrict__ sb, f16* __restrict__ Wt) {
  int tid = blockIdx.x * 256 + threadIdx.x;
  if (tid >= I * O) return;
  int o = tid / I, i = tid % I;             // i fastest -> coalesced Wt writes
  Wt[(size_t)o * (I * 9) + (size_t)I * 8 + i] = (f16)sb[(size_t)i * O + o];
}

// ---------------------------------------------------------------------------
// 8-slot cubic B-spline basis (verified in R1-R3, absmax 0.0625).
// ---------------------------------------------------------------------------
__device__ __forceinline__ f16x8 spline8(float h) {
  float v = __builtin_fmaf(2.5f, h, 5.5f);
  float c = floorf(v);
  float f = v - c;
  float f2 = f * f, f3 = f2 * f;
  float b3 = f3 * (1.f / 6.f);
  float t = 1.f - f;
  float b0 = t * t * t * (1.f / 6.f);
  float b1 = (2.f / 3.f) - f2 + 0.5f * f3;
  float b2 = 1.f - b0 - b1 - b3;
  int base = 3 - (int)c;
  f16x8 o;
#pragma unroll
  for (int g = 0; g < 8; ++g) {
    int d = base + g;                         // 0..3 -> b_d else 0
    float lo = (d & 2) ? b2 : b0;
    float hi = (d & 2) ? b3 : b1;
    float val = (d & 1) ? hi : lo;
    o[g] = (f16)(((unsigned)d <= 3u) ? val : 0.f);
  }
  return o;
}

// ---------------------------------------------------------------------------
// Fused KAN GEMM, 128(M) x 256(N) tile, BK=64. C[M,N](f32) =
// KanAct(H)[M,9I] @ W[N,9I]^T. A-tile computed on the fly from H into
// swizzled LDS; B staged via global_load_lds width-16.
// 4 waves in 2x2; each wave 64x128 = 4x8 frags of mfma_f32_16x16x32_f16.
// N-tile=256 keeps per-k-tile MFMA (~2483 cyc/CU) above A-gen VALU
// (~960 cyc/CU) so activation compute hides under the MFMA shadow (m114).
// LDS XOR swizzle on 16B chunks: LDS[r][c] = logical chunk c ^ (r&7)
// (R2: conflicts 3e7 -> 0). ATOMIC=1: atomicAdd epilogue for split-K.
// ---------------------------------------------------------------------------
template <int I, int ATOMIC>
__global__ __launch_bounds__(256, 2) void gemm_kan(const float* __restrict__ H,
                                                   const f16* __restrict__ W,
                                                   float* __restrict__ C,
                                                   int N, int kChunk) {
  constexpr int K = 9 * I;
  constexpr int KB = 8 * I;                   // spline/base boundary (mult 64)
  __shared__ __align__(16) f16 sA[128 * 64];  // 16 KB
  __shared__ __align__(16) f16 sB[256 * 64];  // 32 KB
  const int t = threadIdx.x;
  const int n0 = blockIdx.x * 256;
  const int m0 = blockIdx.y * 128;
  const int kBeg = blockIdx.z * kChunk;
  const int kEnd = kBeg + kChunk;
  const int w = t >> 6, lane = t & 63;
  const int wm = (w >> 1) * 64, wn = (w & 1) * 128;
  const int lr = lane & 15, lq = lane >> 4;
  const int wbase = t & 192;                  // w*64, wave-uniform
  const int srow = t >> 3;                    // staging row 0..31 (q adds 32)
  const int j_ = t & 7;                       // chunk col 0..7
  const int js = j_ ^ (srow & 7);             // swizzled chunk col

  f32x4 acc[4][8] = {};
  const f16* Wrow = W + (size_t)(n0 + srow) * K + js * 8;
  const float* Hrow = H + (size_t)(m0 + srow) * I;

  for (int k0 = kBeg; k0 < kEnd; k0 += 64) {
    // B tile: 256 rows x 64 cols, async global->LDS, 8 rounds of 32 rows
#pragma unroll
    for (int q = 0; q < 8; ++q)
      async16(Wrow + (size_t)(q * 32) * K + k0, &sB[(q * 256 + wbase) * 8]);

    // A tile: compute from H. Whole block takes same branch (k0-uniform).
    if (k0 < KB) {
      const int i0 = k0 >> 3;                 // tile covers inputs i0..i0+7
      float hq[4];
#pragma unroll
      for (int q = 0; q < 4; ++q)
        hq[q] = Hrow[(size_t)(q * 32) * I + i0 + j_];
#pragma unroll
      for (int q = 0; q < 4; ++q)
        *(f16x8*)&sA[((q * 32 + srow) * 8 + js) * 8] = spline8(hq[q]);
    } else {
      const int c0 = (k0 - KB) + j_ * 8;      // 8 consecutive silu inputs
      f32x4 ha[4][2];
#pragma unroll
      for (int q = 0; q < 4; ++q) {
        const f32x4* p = (const f32x4*)(Hrow + (size_t)(q * 32) * I + c0);
        ha[q][0] = p[0];
        ha[q][1] = p[1];
      }
#pragma unroll
      for (int q = 0; q < 4; ++q) {
        f16x8 o;
#pragma unroll
        for (int s = 0; s < 8; ++s) {
          float h = ha[q][s >> 2][s & 3];
          o[s] = (f16)(h / (1.f + __expf(-h)));
        }
        *(f16x8*)&sA[((q * 32 + srow) * 8 + js) * 8] = o;
      }
    }
    __syncthreads();
#pragma unroll
    for (int kk = 0; kk < 64; kk += 32) {
      f16x8 av[4], bv[8];
#pragma unroll
      for (int i = 0; i < 4; ++i) {
        const int ra = wm + i * 16 + lr;
        const int ca = ((kk >> 3) + lq) ^ (ra & 7);
        av[i] = *(const f16x8*)&sA[ra * 64 + ca * 8];
      }
#pragma unroll
      for (int j = 0; j < 8; ++j) {
        const int rb = wn + j * 16 + lr;
        const int cb = ((kk >> 3) + lq) ^ (rb & 7);
        bv[j] = *(const f16x8*)&sB[rb * 64 + cb * 8];
      }
#pragma unroll
      for (int i = 0; i < 4; ++i)
#pragma unroll
        for (int j = 0; j < 8; ++j)
          acc[i][j] = __builtin_amdgcn_mfma_f32_16x16x32_f16(av[i], bv[j],
                                                             acc[i][j], 0, 0, 0);
    }
    __syncthreads();
  }

#pragma unroll
  for (int i = 0; i < 4; ++i) {
#pragma unroll
    for (int j = 0; j < 8; ++j) {
      const int col = n0 + wn + j * 16 + lr;
#pragma unroll
      for (int r = 0; r < 4; ++r) {
        const int row = m0 + wm + i * 16 + lq * 4 + r;
        if (ATOMIC)
          atomicAdd(&C[(size_t)row * N + col], acc[i][j][r]);
        else
          C[(size_t)row * N + col] = acc[i][j][r];
      }
    }
  }
}

// ---------------------------------------------------------------------------
extern "C" void kernel_launch(void* const* d_in, const int* in_sizes, int n_in,
                              void* d_out, int out_size, void* d_ws,
                              size_t ws_size, hipStream_t stream) {
  const float* x     = (const float*)d_in[0];
  const float* coef1 = (const float*)d_in[1];
  const float* sb1   = (const float*)d_in[2];
  const float* ssp1  = (const float*)d_in[3];
  const float* coef2 = (const float*)d_in[4];
  const float* sb2   = (const float*)d_in[5];
  const float* ssp2  = (const float*)d_in[6];

  const int Mtot = 8192;
  const int I1 = 512, O1 = 2048, K1 = I1 * 9;   // 4608
  const int I2 = 2048, O2 = 512, K2 = I2 * 9;   // 18432

  char* ws = (char*)d_ws;
  const size_t szW1 = (size_t)O1 * K1 * sizeof(f16);     // 18.9 MB
  const size_t szW2 = (size_t)O2 * K2 * sizeof(f16);     // 18.9 MB
  const size_t szH  = (size_t)Mtot * O1 * sizeof(float); // 67.1 MB
  if (ws_size < szW1 + szW2 + szH) return;  // cannot run; fail visibly
  f16*   W1 = (f16*)ws;
  f16*   W2 = (f16*)(ws + szW1);
  float* h1 = (float*)(ws + szW1 + szW2);

  // weight prep
  {
    int n1 = I1 * O1;
    prep_coef<512, 2048><<<(n1 + 255) / 256, 256, 0, stream>>>(coef1, ssp1, W1);
    prep_base<512, 2048><<<(n1 + 255) / 256, 256, 0, stream>>>(sb1, W1);
    int n2 = I2 * O2;
    prep_coef<2048, 512><<<(n2 + 255) / 256, 256, 0, stream>>>(coef2, ssp2, W2);
    prep_base<2048, 512><<<(n2 + 255) / 256, 256, 0, stream>>>(sb2, W2);
  }

  // layer 1: h1 = KanAct(x) @ W1^T   — grid 8x64 = 512 blocks, 2/CU
  gemm_kan<512, 0><<<dim3(O1 / 256, Mtot / 128, 1), 256, 0, stream>>>(
      x, W1, h1, O1, K1);

  // layer 2: out = KanAct(h1) @ W2^T — split-K=4, grid 2x64x4 = 512 blocks
  hipMemsetAsync(d_out, 0, (size_t)Mtot * O2 * sizeof(float), stream);
  const int SK = 4;
  gemm_kan<2048, 1><<<dim3(O2 / 256, Mtot / 128, SK), 256, 0, stream>>>(
      h1, W2, (float*)d_out, O2, K2 / SK);
}

// Round 6
// 546.242 us; speedup vs baseline: 1.4890x; 1.0996x over previous
//
#include <hip/hip_runtime.h>
#include <cstdint>
#include <cstddef>

typedef _Float16 f16;
typedef _Float16 f16x8 __attribute__((ext_vector_type(8)));
typedef float f32x4 __attribute__((ext_vector_type(4)));

// ---------------------------------------------------------------------------
// async global->LDS, 16B per lane. LDS dest is wave-uniform base + lane*16.
// ---------------------------------------------------------------------------
__device__ __forceinline__ void async16(const void* g, void* l) {
  __builtin_amdgcn_global_load_lds(
      (const __attribute__((address_space(1))) unsigned int*)g,
      (__attribute__((address_space(3))) unsigned int*)l,
      16, 0, 0);
}

// ---------------------------------------------------------------------------
// Weight prep: Wt[o][i*8+g] = coef[i][o][g] * ssp[i][o]   (Wt is [O][K], K=I*9)
// ---------------------------------------------------------------------------
template <int I, int O>
__global__ void prep_coef(const float* __restrict__ coef,
                          const float* __restrict__ ssp,
                          f16* __restrict__ Wt) {
  int tid = blockIdx.x * 256 + threadIdx.x;
  if (tid >= I * O) return;
  int i = tid / O, o = tid % O;             // o fastest -> coalesced coef reads
  float s = ssp[tid];
  const float* c = coef + (size_t)tid * 8;
  f16x8 out;
#pragma unroll
  for (int g = 0; g < 8; ++g) out[g] = (f16)(c[g] * s);
  *(f16x8*)(Wt + (size_t)o * (I * 9) + (size_t)i * 8) = out;
}

// Wt[o][I*8+i] = sb[i][o]
template <int I, int O>
__global__ void prep_base(const float* __restrict__ sb, f16* __restrict__ Wt) {
  int tid = blockIdx.x * 256 + threadIdx.x;
  if (tid >= I * O) return;
  int o = tid / I, i = tid % I;             // i fastest -> coalesced Wt writes
  Wt[(size_t)o * (I * 9) + (size_t)I * 8 + i] = (f16)sb[(size_t)i * O + o];
}

// ---------------------------------------------------------------------------
// 8-slot cubic B-spline basis, packed-shift form (same math as the R1-R4
// select-ladder version, absmax 0.0625). Nonzero slots g = c-3..c hold
// b0=(1-f)^3/6, b1=2/3-f^2+f^3/2, b2=1-b0-b1-b3, b3=f^3/6 with c=floor(v),
// f=v-c, v=2.5h+5.5. Placement: pack b0..b3 as 4 f16 (cvt_pkrtz) and shift
// the 64-bit group into a 128-bit window by (c-3)*16 bits. c outside [0,10]
// -> all slots zero (handled by shift guards). ~30 VALU vs ~60 before.
// ---------------------------------------------------------------------------
__device__ __forceinline__ f16x8 spline8(float h) {
  float v = __builtin_fmaf(2.5f, h, 5.5f);
  float c = floorf(v);
  float f = v - c;
  float f2 = f * f, f3 = f2 * f;
  float b3 = f3 * (1.f / 6.f);
  float t = 1.f - f;
  float b0 = t * t * t * (1.f / 6.f);
  float b1 = (2.f / 3.f) - f2 + 0.5f * f3;
  float b2 = 1.f - b0 - b1 - b3;
  // cvt_pkrtz returns __fp16x2; same 32-bit layout as _Float16x2 -> bit_cast
  unsigned int u01 =
      __builtin_bit_cast(unsigned int, __builtin_amdgcn_cvt_pkrtz(b0, b1));
  unsigned int u23 =
      __builtin_bit_cast(unsigned int, __builtin_amdgcn_cvt_pkrtz(b2, b3));
  unsigned long long pk = (unsigned long long)u01 |
                          ((unsigned long long)u23 << 32);
  int ci = (int)c;
  int s = (ci - 3) * 16;                // bit offset of slot c-3
  __uint128_t r = 0;
  if (s >= 0) {
    if (s < 128) r = (__uint128_t)pk << s;          // s in [0,112]: defined
  } else {
    int q = -s;                                      // 16..inf
    if (q < 64) r = (__uint128_t)(pk >> q);          // drop g<0 slots
  }
  return __builtin_bit_cast(f16x8, r);
}

// ---------------------------------------------------------------------------
// Fused KAN GEMM, 128(M) x 256(N) tile, BK=64. C[M,N](f32) =
// KanAct(H)[M,9I] @ W[N,9I]^T. A-tile computed on the fly from H into
// swizzled LDS; B staged via global_load_lds width-16.
// 4 waves in 2x2; each wave 64x128 = 4x8 frags of mfma_f32_16x16x32_f16.
// Register budget note (R4): acc = 128 AGPR + ~108 VGPR -> 2 waves/SIMD,
// 2 blocks/CU is a hard register lock; grid/split-K can't raise occupancy.
// Hence: minimize the serial A-gen phase between barriers (cheap spline8 +
// H prefetch hidden under the barrier's vmcnt drain).
// LDS XOR swizzle on 16B chunks: LDS[r][c] = logical chunk c ^ (r&7)
// (R2: conflicts 3e7 -> 0). ATOMIC=1: atomicAdd epilogue for split-K.
// ---------------------------------------------------------------------------
template <int I, int ATOMIC>
__global__ __launch_bounds__(256, 2) void gemm_kan(const float* __restrict__ H,
                                                   const f16* __restrict__ W,
                                                   float* __restrict__ C,
                                                   int N, int kChunk) {
  constexpr int K = 9 * I;
  constexpr int KB = 8 * I;                   // spline/base boundary (mult 64)
  __shared__ __align__(16) f16 sA[128 * 64];  // 16 KB
  __shared__ __align__(16) f16 sB[256 * 64];  // 32 KB
  const int t = threadIdx.x;
  const int n0 = blockIdx.x * 256;
  const int m0 = blockIdx.y * 128;
  const int kBeg = blockIdx.z * kChunk;
  const int kEnd = kBeg + kChunk;
  const int w = t >> 6, lane = t & 63;
  const int wm = (w >> 1) * 64, wn = (w & 1) * 128;
  const int lr = lane & 15, lq = lane >> 4;
  const int wbase = t & 192;                  // w*64, wave-uniform
  const int srow = t >> 3;                    // staging row 0..31 (q adds 32)
  const int j_ = t & 7;                       // chunk col 0..7
  const int js = j_ ^ (srow & 7);             // swizzled chunk col

  f32x4 acc[4][8] = {};
  const f16* Wrow = W + (size_t)(n0 + srow) * K + js * 8;
  const float* Hrow = H + (size_t)(m0 + srow) * I;

  // prefetch H for the first spline k-tile
  float hs[4];
  if (kBeg < KB) {
    const int i0 = kBeg >> 3;
#pragma unroll
    for (int q = 0; q < 4; ++q)
      hs[q] = Hrow[(size_t)(q * 32) * I + i0 + j_];
  }

  for (int k0 = kBeg; k0 < kEnd; k0 += 64) {
    // B tile: 256 rows x 64 cols, async global->LDS, 8 rounds of 32 rows
#pragma unroll
    for (int q = 0; q < 8; ++q)
      async16(Wrow + (size_t)(q * 32) * K + k0, &sB[(q * 256 + wbase) * 8]);

    // A tile: compute from prefetched H. Branch is k0-uniform per block.
    if (k0 < KB) {
#pragma unroll
      for (int q = 0; q < 4; ++q)
        *(f16x8*)&sA[((q * 32 + srow) * 8 + js) * 8] = spline8(hs[q]);
      // prefetch next spline tile's H; lands under this tile's barrier drain
      const int kn = k0 + 64;
      if (kn < kEnd && kn < KB) {
        const int i0n = kn >> 3;
#pragma unroll
        for (int q = 0; q < 4; ++q)
          hs[q] = Hrow[(size_t)(q * 32) * I + i0n + j_];
      }
    } else {
      const int c0 = (k0 - KB) + j_ * 8;      // 8 consecutive silu inputs
      f32x4 ha[4][2];
#pragma unroll
      for (int q = 0; q < 4; ++q) {
        const f32x4* p = (const f32x4*)(Hrow + (size_t)(q * 32) * I + c0);
        ha[q][0] = p[0];
        ha[q][1] = p[1];
      }
#pragma unroll
      for (int q = 0; q < 4; ++q) {
        f16x8 o;
#pragma unroll
        for (int s = 0; s < 8; ++s) {
          float h = ha[q][s >> 2][s & 3];
          o[s] = (f16)(h / (1.f + __expf(-h)));
        }
        *(f16x8*)&sA[((q * 32 + srow) * 8 + js) * 8] = o;
      }
    }
    __syncthreads();
#pragma unroll
    for (int kk = 0; kk < 64; kk += 32) {
      f16x8 av[4], bv[8];
#pragma unroll
      for (int i = 0; i < 4; ++i) {
        const int ra = wm + i * 16 + lr;
        const int ca = ((kk >> 3) + lq) ^ (ra & 7);
        av[i] = *(const f16x8*)&sA[ra * 64 + ca * 8];
      }
#pragma unroll
      for (int j = 0; j < 8; ++j) {
        const int rb = wn + j * 16 + lr;
        const int cb = ((kk >> 3) + lq) ^ (rb & 7);
        bv[j] = *(const f16x8*)&sB[rb * 64 + cb * 8];
      }
#pragma unroll
      for (int i = 0; i < 4; ++i)
#pragma unroll
        for (int j = 0; j < 8; ++j)
          acc[i][j] = __builtin_amdgcn_mfma_f32_16x16x32_f16(av[i], bv[j],
                                                             acc[i][j], 0, 0, 0);
    }
    __syncthreads();
  }

#pragma unroll
  for (int i = 0; i < 4; ++i) {
#pragma unroll
    for (int j = 0; j < 8; ++j) {
      const int col = n0 + wn + j * 16 + lr;
#pragma unroll
      for (int r = 0; r < 4; ++r) {
        const int row = m0 + wm + i * 16 + lq * 4 + r;
        if (ATOMIC)
          atomicAdd(&C[(size_t)row * N + col], acc[i][j][r]);
        else
          C[(size_t)row * N + col] = acc[i][j][r];
      }
    }
  }
}

// ---------------------------------------------------------------------------
extern "C" void kernel_launch(void* const* d_in, const int* in_sizes, int n_in,
                              void* d_out, int out_size, void* d_ws,
                              size_t ws_size, hipStream_t stream) {
  const float* x     = (const float*)d_in[0];
  const float* coef1 = (const float*)d_in[1];
  const float* sb1   = (const float*)d_in[2];
  const float* ssp1  = (const float*)d_in[3];
  const float* coef2 = (const float*)d_in[4];
  const float* sb2   = (const float*)d_in[5];
  const float* ssp2  = (const float*)d_in[6];

  const int Mtot = 8192;
  const int I1 = 512, O1 = 2048, K1 = I1 * 9;   // 4608
  const int I2 = 2048, O2 = 512, K2 = I2 * 9;   // 18432

  char* ws = (char*)d_ws;
  const size_t szW1 = (size_t)O1 * K1 * sizeof(f16);     // 18.9 MB
  const size_t szW2 = (size_t)O2 * K2 * sizeof(f16);     // 18.9 MB
  const size_t szH  = (size_t)Mtot * O1 * sizeof(float); // 67.1 MB
  if (ws_size < szW1 + szW2 + szH) return;  // cannot run; fail visibly
  f16*   W1 = (f16*)ws;
  f16*   W2 = (f16*)(ws + szW1);
  float* h1 = (float*)(ws + szW1 + szW2);

  // weight prep
  {
    int n1 = I1 * O1;
    prep_coef<512, 2048><<<(n1 + 255) / 256, 256, 0, stream>>>(coef1, ssp1, W1);
    prep_base<512, 2048><<<(n1 + 255) / 256, 256, 0, stream>>>(sb1, W1);
    int n2 = I2 * O2;
    prep_coef<2048, 512><<<(n2 + 255) / 256, 256, 0, stream>>>(coef2, ssp2, W2);
    prep_base<2048, 512><<<(n2 + 255) / 256, 256, 0, stream>>>(sb2, W2);
  }

  // layer 1: h1 = KanAct(x) @ W1^T   — grid 8x64 = 512 blocks, 2/CU
  gemm_kan<512, 0><<<dim3(O1 / 256, Mtot / 128, 1), 256, 0, stream>>>(
      x, W1, h1, O1, K1);

  // layer 2: out = KanAct(h1) @ W2^T — split-K=4, grid 2x64x4 = 512 blocks
  (void)hipMemsetAsync(d_out, 0, (size_t)Mtot * O2 * sizeof(float), stream);
  const int SK = 4;
  gemm_kan<2048, 1><<<dim3(O2 / 256, Mtot / 128, SK), 256, 0, stream>>>(
      h1, W2, (float*)d_out, O2, K2 / SK);
}

// Round 7
// 522.130 us; speedup vs baseline: 1.5578x; 1.0462x over previous
//
#include <hip/hip_runtime.h>
#include <cstdint>
#include <cstddef>

typedef _Float16 f16;
typedef _Float16 f16x8 __attribute__((ext_vector_type(8)));
typedef float f32x4 __attribute__((ext_vector_type(4)));

// ---------------------------------------------------------------------------
// W is stored fragment-tiled for mfma_f32_16x16x32_f16's B operand:
// lane l of a wave holds B[n = nf*16 + (l&15)][k = kb*32 + (l>>4)*8 + j].
// Element (n,k) lives at flat f16 index
//   ((n>>4)*(K/32) + (k>>5))*512 + (((k>>3)&3)*16 + (n&15))*8 + (k&7)
// so a wave loads one fragment as ONE coalesced global_load_dwordx4
// (lane l reads tile_base + l*16 bytes). This removes B from LDS entirely —
// R6 analysis: 192 ds_read_b128/CU/iter ~2300 cyc was the saturated pipe.
// ---------------------------------------------------------------------------

// Wt tile for coef: k = i*8+g  ->  kb=i>>2, lane=(i&3)*16+(o&15), elem g
template <int I, int O>
__global__ void prep_coef(const float* __restrict__ coef,
                          const float* __restrict__ ssp,
                          f16* __restrict__ Wt) {
  constexpr int K32 = (9 * I) / 32;
  int tid = blockIdx.x * 256 + threadIdx.x;
  if (tid >= I * O) return;
  int i = tid / O, o = tid % O;             // o fastest -> coalesced coef reads
  float s = ssp[tid];
  const float* c = coef + (size_t)tid * 8;
  f16x8 out;
#pragma unroll
  for (int g = 0; g < 8; ++g) out[g] = (f16)(c[g] * s);
  size_t addr = ((size_t)(o >> 4) * K32 + (i >> 2)) * 512 +
                (size_t)(((i & 3) * 16) + (o & 15)) * 8;
  *(f16x8*)(Wt + addr) = out;
}

// Wt tile for base: k = 8I+i -> kb=I/4+(i>>5), lane=((i>>3)&3)*16+(o&15), elem i&7
// Each thread handles 8 consecutive i (one f16x8 chunk) for one o.
template <int I, int O>
__global__ void prep_base(const float* __restrict__ sb, f16* __restrict__ Wt) {
  constexpr int K32 = (9 * I) / 32;
  int tid = blockIdx.x * 256 + threadIdx.x;
  if (tid >= (I / 8) * O) return;
  int i8 = tid / O, o = tid % O;            // o fastest -> coalesced writes
  f16x8 out;
#pragma unroll
  for (int s = 0; s < 8; ++s)
    out[s] = (f16)sb[(size_t)(i8 * 8 + s) * O + o];
  size_t addr = ((size_t)(o >> 4) * K32 + (I / 4) + (i8 >> 2)) * 512 +
                (size_t)(((i8 & 3) * 16) + (o & 15)) * 8;
  *(f16x8*)(Wt + addr) = out;
}

// ---------------------------------------------------------------------------
// 8-slot cubic B-spline basis, packed-shift form (verified R6, absmax 0.0625).
// ---------------------------------------------------------------------------
__device__ __forceinline__ f16x8 spline8(float h) {
  float v = __builtin_fmaf(2.5f, h, 5.5f);
  float c = floorf(v);
  float f = v - c;
  float f2 = f * f, f3 = f2 * f;
  float b3 = f3 * (1.f / 6.f);
  float t = 1.f - f;
  float b0 = t * t * t * (1.f / 6.f);
  float b1 = (2.f / 3.f) - f2 + 0.5f * f3;
  float b2 = 1.f - b0 - b1 - b3;
  unsigned int u01 =
      __builtin_bit_cast(unsigned int, __builtin_amdgcn_cvt_pkrtz(b0, b1));
  unsigned int u23 =
      __builtin_bit_cast(unsigned int, __builtin_amdgcn_cvt_pkrtz(b2, b3));
  unsigned long long pk = (unsigned long long)u01 |
                          ((unsigned long long)u23 << 32);
  int ci = (int)c;
  int s = (ci - 3) * 16;                // bit offset of slot c-3
  __uint128_t r = 0;
  if (s >= 0) {
    if (s < 128) r = (__uint128_t)pk << s;
  } else {
    int q = -s;
    if (q < 64) r = (__uint128_t)(pk >> q);
  }
  return __builtin_bit_cast(f16x8, r);
}

// ---------------------------------------------------------------------------
// Fused KAN GEMM, 128(M) x 256(N) tile, BK=64. C[M,N](f32) =
// KanAct(H)[M,9I] @ W[N,9I]^T, W fragment-tiled (see prep_*).
// A-tile computed on the fly into swizzled LDS (16 KB, XOR-swizzled,
// conflicts=0 per R2); B-fragments loaded straight from global per MFMA
// (L1/L2-resident: W slice ~2.4 MB/XCD). bv(kk=0) issues before A-gen
// (latency under VALU); bv(kk=32) issues under MFMA half 1.
// 4 waves 2x2, each 64x128 = 4x8 frags of mfma_f32_16x16x32_f16; 128 AGPR
// acc -> 2 blocks/CU register-locked. ATOMIC=1: atomicAdd split-K epilogue.
// ---------------------------------------------------------------------------
template <int I, int ATOMIC>
__global__ __launch_bounds__(256, 2) void gemm_kan(const float* __restrict__ H,
                                                   const f16* __restrict__ W,
                                                   float* __restrict__ C,
                                                   int N, int kChunk) {
  constexpr int K = 9 * I;
  constexpr int KB = 8 * I;                   // spline/base boundary (mult 64)
  constexpr int K32 = K / 32;
  __shared__ __align__(16) f16 sA[128 * 64];  // 16 KB
  const int t = threadIdx.x;
  const int n0 = blockIdx.x * 256;
  const int m0 = blockIdx.y * 128;
  const int kBeg = blockIdx.z * kChunk;
  const int kEnd = kBeg + kChunk;
  const int w = t >> 6, lane = t & 63;
  const int wm = (w >> 1) * 64, wn = (w & 1) * 128;
  const int lr = lane & 15, lq = lane >> 4;
  const int srow = t >> 3;                    // staging row 0..31 (q adds 32)
  const int j_ = t & 7;                       // chunk col 0..7
  const int js = j_ ^ (srow & 7);             // swizzled chunk col

  f32x4 acc[4][8] = {};
  const float* Hrow = H + (size_t)(m0 + srow) * I;
  // wave's fragment-tiled W base: n-frag (n0+wn)>>4, + lane*8 elems
  const f16* Pw = W + (size_t)((n0 + wn) >> 4) * K32 * 512 + lane * 8;

  // prefetch H for the first spline k-tile
  float hs[4];
  if (kBeg < KB) {
    const int i0 = kBeg >> 3;
#pragma unroll
    for (int q = 0; q < 4; ++q)
      hs[q] = Hrow[(size_t)(q * 32) * I + i0 + j_];
  }

  for (int k0 = kBeg; k0 < kEnd; k0 += 64) {
    const int kb0 = k0 >> 5;
    // B frags for kk=0: 8 coalesced dwordx4 loads, issued before A-gen so
    // their L2 latency hides under the spline/silu VALU work.
    f16x8 bv0[8];
#pragma unroll
    for (int j = 0; j < 8; ++j)
      bv0[j] = *(const f16x8*)(Pw + ((size_t)j * K32 + kb0) * 512);

    // A tile: compute from prefetched H into swizzled sA (k0-uniform branch).
    if (k0 < KB) {
#pragma unroll
      for (int q = 0; q < 4; ++q)
        *(f16x8*)&sA[((q * 32 + srow) * 8 + js) * 8] = spline8(hs[q]);
      const int kn = k0 + 64;
      if (kn < kEnd && kn < KB) {
        const int i0n = kn >> 3;
#pragma unroll
        for (int q = 0; q < 4; ++q)
          hs[q] = Hrow[(size_t)(q * 32) * I + i0n + j_];
      }
    } else {
      const int c0 = (k0 - KB) + j_ * 8;      // 8 consecutive silu inputs
      f32x4 ha[4][2];
#pragma unroll
      for (int q = 0; q < 4; ++q) {
        const f32x4* p = (const f32x4*)(Hrow + (size_t)(q * 32) * I + c0);
        ha[q][0] = p[0];
        ha[q][1] = p[1];
      }
#pragma unroll
      for (int q = 0; q < 4; ++q) {
        f16x8 o;
#pragma unroll
        for (int s = 0; s < 8; ++s) {
          float h = ha[q][s >> 2][s & 3];
          o[s] = (f16)(h / (1.f + __expf(-h)));
        }
        *(f16x8*)&sA[((q * 32 + srow) * 8 + js) * 8] = o;
      }
    }
    __syncthreads();

    // kk = 0 half: av from LDS, bv0 from registers; issue bv1 under MFMA.
    f16x8 av[4], bv1[8];
#pragma unroll
    for (int i = 0; i < 4; ++i) {
      const int ra = wm + i * 16 + lr;
      const int ca = lq ^ (ra & 7);
      av[i] = *(const f16x8*)&sA[ra * 64 + ca * 8];
    }
#pragma unroll
    for (int j = 0; j < 8; ++j)
      bv1[j] = *(const f16x8*)(Pw + ((size_t)j * K32 + kb0 + 1) * 512);
#pragma unroll
    for (int i = 0; i < 4; ++i)
#pragma unroll
      for (int j = 0; j < 8; ++j)
        acc[i][j] = __builtin_amdgcn_mfma_f32_16x16x32_f16(av[i], bv0[j],
                                                           acc[i][j], 0, 0, 0);
    // kk = 32 half
#pragma unroll
    for (int i = 0; i < 4; ++i) {
      const int ra = wm + i * 16 + lr;
      const int ca = (4 + lq) ^ (ra & 7);
      av[i] = *(const f16x8*)&sA[ra * 64 + ca * 8];
    }
#pragma unroll
    for (int i = 0; i < 4; ++i)
#pragma unroll
      for (int j = 0; j < 8; ++j)
        acc[i][j] = __builtin_amdgcn_mfma_f32_16x16x32_f16(av[i], bv1[j],
                                                           acc[i][j], 0, 0, 0);
    __syncthreads();
  }

#pragma unroll
  for (int i = 0; i < 4; ++i) {
#pragma unroll
    for (int j = 0; j < 8; ++j) {
      const int col = n0 + wn + j * 16 + lr;
#pragma unroll
      for (int r = 0; r < 4; ++r) {
        const int row = m0 + wm + i * 16 + lq * 4 + r;
        if (ATOMIC)
          atomicAdd(&C[(size_t)row * N + col], acc[i][j][r]);
        else
          C[(size_t)row * N + col] = acc[i][j][r];
      }
    }
  }
}

// ---------------------------------------------------------------------------
extern "C" void kernel_launch(void* const* d_in, const int* in_sizes, int n_in,
                              void* d_out, int out_size, void* d_ws,
                              size_t ws_size, hipStream_t stream) {
  const float* x     = (const float*)d_in[0];
  const float* coef1 = (const float*)d_in[1];
  const float* sb1   = (const float*)d_in[2];
  const float* ssp1  = (const float*)d_in[3];
  const float* coef2 = (const float*)d_in[4];
  const float* sb2   = (const float*)d_in[5];
  const float* ssp2  = (const float*)d_in[6];

  const int Mtot = 8192;
  const int I1 = 512, O1 = 2048, K1 = I1 * 9;   // 4608
  const int I2 = 2048, O2 = 512, K2 = I2 * 9;   // 18432

  char* ws = (char*)d_ws;
  const size_t szW1 = (size_t)O1 * K1 * sizeof(f16);     // 18.9 MB
  const size_t szW2 = (size_t)O2 * K2 * sizeof(f16);     // 18.9 MB
  const size_t szH  = (size_t)Mtot * O1 * sizeof(float); // 67.1 MB
  if (ws_size < szW1 + szW2 + szH) return;  // cannot run; fail visibly
  f16*   W1 = (f16*)ws;
  f16*   W2 = (f16*)(ws + szW1);
  float* h1 = (float*)(ws + szW1 + szW2);

  // weight prep (fragment-tiled layout)
  {
    int n1 = I1 * O1;
    prep_coef<512, 2048><<<(n1 + 255) / 256, 256, 0, stream>>>(coef1, ssp1, W1);
    prep_base<512, 2048><<<(n1 / 8 + 255) / 256, 256, 0, stream>>>(sb1, W1);
    int n2 = I2 * O2;
    prep_coef<2048, 512><<<(n2 + 255) / 256, 256, 0, stream>>>(coef2, ssp2, W2);
    prep_base<2048, 512><<<(n2 / 8 + 255) / 256, 256, 0, stream>>>(sb2, W2);
  }

  // layer 1: h1 = KanAct(x) @ W1^T   — grid 8x64 = 512 blocks, 2/CU
  gemm_kan<512, 0><<<dim3(O1 / 256, Mtot / 128, 1), 256, 0, stream>>>(
      x, W1, h1, O1, K1);

  // layer 2: out = KanAct(h1) @ W2^T — split-K=4, grid 2x64x4 = 512 blocks
  (void)hipMemsetAsync(d_out, 0, (size_t)Mtot * O2 * sizeof(float), stream);
  const int SK = 4;
  gemm_kan<2048, 1><<<dim3(O2 / 256, Mtot / 128, SK), 256, 0, stream>>>(
      h1, W2, (float*)d_out, O2, K2 / SK);
}